// Round 7
// baseline (63.721 us; speedup 1.0000x reference)
//
#include <hip/hip_runtime.h>
#include <math.h>

#define DIM 256
#define TILE 32

// ---------------------------------------------------------------------------
// Fully fused kernel, round-7 (= round-6 restructure with compile fix).
// Per block: build Pauli-transfer table T[q][p] in LDS (validated rounds 2-5),
// then loop over 32-row tiles:
//   A: stage x tile to LDS; serial per-thread GEMV (8 thr/row: q x k-half),
//      1 shfl combine + 3 shfl gather -> every thread holds acc[0..3] for row.
//   B: per-thread middle (tanh, LN(4), Bloch) -> bs[row][12] (1 writer/row).
//   C: pairwise epilogue (2 rows/wave-group): Pauli products + z-GEMV +
//      32-lane reduce + Wout epilogue; x read back from the LDS tile.
// amdgpu_waves_per_eu(3,3) pins the allocator's occupancy target (3 blocks/CU
// by LDS) so hoisted fragments stay register-resident (round-4/5 lesson:
// launch_bounds alone lets the allocator rematerialize invariant loads).
// ---------------------------------------------------------------------------

__device__ __forceinline__ float sel3(int p, float vx, float vy, float vz)
{
  float r = 1.0f;
  r = (p == 1) ? vx : r;
  r = (p == 2) ? vy : r;
  r = (p == 3) ? vz : r;
  return r;
}

__global__ __launch_bounds__(256)
__attribute__((amdgpu_waves_per_eu(3, 3)))
void qlayer_fused_kernel(
    const float* __restrict__ x,
    const float* __restrict__ Win,
    const float* __restrict__ b_in,
    const float* __restrict__ gamma,
    const float* __restrict__ beta,
    const float* __restrict__ qw,
    const float* __restrict__ Wout,
    const float* __restrict__ b_out,
    float* __restrict__ out,
    int B)
{
  __shared__ float xs[TILE][260];   // x tile; rows 16B-aligned, bank-spread
  __shared__ float ws[4][264];      // Win staged (264: q-rows on distinct banks)
  __shared__ float Tl[1024];        // Pauli-transfer table, flat [q*256 + p]
  __shared__ float bs[TILE][12];    // Bloch vectors per row

  const int tid = threadIdx.x;

  // ---- stage Win into LDS (one-time) ----
  {
    const int q = tid >> 6, k4 = tid & 63;
    *reinterpret_cast<float4*>(&ws[q][k4 * 4]) =
        *reinterpret_cast<const float4*>(&Win[q * 256 + k4 * 4]);
  }

  // ================= Phase 0: build T in LDS (validated) ===================
  // V/O scratch aliased into xs (xs unused until first tile stage).
  {
    float* Vr  = &xs[0][0];
    float* Vi  = Vr + 256;
    float* Orr = Vi + 256;
    float* Oii = Orr + 256;
    const int r = tid >> 4, c = tid & 15;

    Vr[r * 16 + c] = (r == c) ? 1.0f : 0.0f;
    Vi[r * 16 + c] = 0.0f;
    __syncthreads();

    #pragma unroll 1
    for (int i = 0; i < 4; ++i) {
      const int cm = 8 >> i;             // control mask (qubit i)
      const int tm = 8 >> ((i + 1) & 3); // target mask (qubit (i+1)%4)
      // CNOT(control=i, target=(i+1)%4): row permutation
      {
        const int k = (r & cm) ? (r ^ tm) : r;
        const float nr = Vr[k * 16 + c], ni = Vi[k * 16 + c];
        __syncthreads();
        Vr[r * 16 + c] = nr; Vi[r * 16 + c] = ni;
        __syncthreads();
      }
      const float w  = qw[4 + i];        // qweights[1][i]
      const float ch = cosf(0.5f * w), sh = sinf(0.5f * w);
      // RY(w) on qubit i
      {
        const int m = 8 >> i;
        const int r0 = r & ~m, r1 = r | m;
        float u0, u1;
        if (r & m) { u0 = sh; u1 = ch; } else { u0 = ch; u1 = -sh; }
        const float nr = u0 * Vr[r0 * 16 + c] + u1 * Vr[r1 * 16 + c];
        const float ni = u0 * Vi[r0 * 16 + c] + u1 * Vi[r1 * 16 + c];
        __syncthreads();
        Vr[r * 16 + c] = nr; Vi[r * 16 + c] = ni;
        __syncthreads();
      }
      // RZ(w) on qubit i (diagonal)
      {
        const int m = 8 >> i;
        const float pr = ch;
        const float pi = (r & m) ? sh : -sh;
        const float vr = Vr[r * 16 + c], vi = Vi[r * 16 + c];
        Vr[r * 16 + c] = pr * vr - pi * vi;
        Vi[r * 16 + c] = pr * vi + pi * vr;
        __syncthreads();
      }
    }

    const float sdep = 1.0f - 4.0f * 0.05f / 3.0f;
    const int p0 = tid >> 6, p1 = (tid >> 4) & 3, p2 = (tid >> 2) & 3, p3 = tid & 3;

    #pragma unroll 1
    for (int q = 0; q < 4; ++q) {
      const int zm = 8 >> q;
      float orr = 0.0f, oii = 0.0f;
      for (int k = 0; k < 16; ++k) {
        const float sgn = (k & zm) ? -1.0f : 1.0f;
        const float ar = Vr[k * 16 + r], ai = -Vi[k * 16 + r];
        const float br = Vr[k * 16 + c], bi2 = Vi[k * 16 + c];
        orr += sgn * (ar * br - ai * bi2);
        oii += sgn * (ar * bi2 + ai * br);
      }
      __syncthreads();
      Orr[r * 16 + c] = orr; Oii[r * 16 + c] = oii;
      __syncthreads();

      float tr = 0.0f;
      for (int n = 0; n < 16; ++n) {
        int m = n;
        float fr = 1.0f, fi = 0.0f;
        #pragma unroll
        for (int i2 = 0; i2 < 4; ++i2) {
          const int a   = (n >> (3 - i2)) & 1;
          const int pi_ = (i2 == 0) ? p0 : (i2 == 1) ? p1 : (i2 == 2) ? p2 : p3;
          if (pi_ == 1) {                    // X
            m ^= (8 >> i2);
          } else if (pi_ == 2) {             // Y
            m ^= (8 >> i2);
            const float s2  = a ? 1.0f : -1.0f;
            const float nfr = -fi * s2, nfi = fr * s2;
            fr = nfr; fi = nfi;
          } else if (pi_ == 3) {             // Z
            if (a) { fr = -fr; fi = -fi; }
          }
        }
        tr += fr * Orr[m * 16 + n] - fi * Oii[m * 16 + n];
      }
      const int nnz = (p0 != 0) + (p1 != 0) + (p2 != 0) + (p3 != 0);
      float scale = 1.0f / 16.0f;
      for (int e = 0; e <= nnz; ++e) scale *= sdep;
      Tl[q * 256 + tid] = tr * scale;
      __syncthreads();
    }
  }

  // ---- hoisted constants (small; pinned by waves_per_eu(3,3)) ----
  const int l   = tid & 31;        // lane within 32-lane row group
  const int grp = (tid >> 5) & 1;  // row within pair (phase C)
  const int wav = tid >> 6;        // wave id within block

  float4 tf[4][2];
  #pragma unroll
  for (int q = 0; q < 4; ++q)
    #pragma unroll
    for (int k2 = 0; k2 < 2; ++k2)
      tf[q][k2] = *reinterpret_cast<const float4*>(&Tl[q * 256 + l * 8 + k2 * 4]);

  float4 woutf[2][4];
  #pragma unroll
  for (int k = 0; k < 2; ++k)
    #pragma unroll
    for (int m = 0; m < 4; ++m)
      woutf[k][m] = *reinterpret_cast<const float4*>(&Wout[(k * 128 + l * 4 + m) * 4]);

  float4 boutf[2];
  #pragma unroll
  for (int k = 0; k < 2; ++k)
    boutf[k] = *reinterpret_cast<const float4*>(&b_out[k * 128 + l * 4]);

  float bi[4], ga[4], be[4], cw0[4], sw0[4], cw1[4], sw1[4];
  #pragma unroll
  for (int i = 0; i < 4; ++i) {
    bi[i] = b_in[i]; ga[i] = gamma[i]; be[i] = beta[i];
    const float w0 = qw[i], w1 = qw[4 + i];
    cw0[i] = cosf(w0); sw0[i] = sinf(w0);
    cw1[i] = cosf(w1); sw1[i] = sinf(w1);
  }

  // phase-A mapping: 8 threads per row (q in bits 1-2, k-half in bit 0)
  const int ar = tid >> 3;         // row 0..31
  const int aq = (tid >> 1) & 3;   // q
  const int ah = tid & 1;          // k-half
  const int q01 = (tid >> 1) & 1;  // q bit 0
  const int q2b = (tid >> 2) & 1;  // q bit 1

  // phase-C string indices (per lane, 8 strings p = l*8 + k2*4 + j)
  const int p0s = l >> 3;
  const int p1s = (l >> 1) & 3;
  const int p2b = (l & 1) << 1;

  const int ntiles = B / TILE;

  #pragma unroll 1
  for (int t = blockIdx.x; t < ntiles; t += gridDim.x) {
    const int r0 = t * TILE;
    __syncthreads();   // xs reuse guard (prev tile C / T-build scratch)

    // ---- A1: stage x tile (32 rows x 256 cols), coalesced ----
    #pragma unroll
    for (int i = 0; i < 8; ++i) {
      const int idx = tid + 256 * i;
      const int row = idx >> 6, c4 = idx & 63;
      *reinterpret_cast<float4*>(&xs[row][c4 * 4]) =
          *reinterpret_cast<const float4*>(&x[(size_t)(r0 + row) * DIM + c4 * 4]);
    }
    __syncthreads();

    // ---- A2: serial GEMV (128 fma/thread) ----
    float acc = 0.0f;
    #pragma unroll
    for (int k4 = 0; k4 < 32; ++k4) {
      const float4 xv = *reinterpret_cast<const float4*>(&xs[ar][ah * 128 + k4 * 4]);
      const float4 wv = *reinterpret_cast<const float4*>(&ws[aq][ah * 128 + k4 * 4]);
      acc += xv.x * wv.x + xv.y * wv.y + xv.z * wv.z + xv.w * wv.w;
    }
    acc += __shfl_xor(acc, 1, 64);            // combine k-halves

    // gather all 4 q's into every thread (3 shuffles + selects)
    const float s2 = __shfl_xor(acc, 2, 64);
    const float vE = q01 ? s2 : acc;          // acc for q & ~1
    const float vO = q01 ? acc : s2;          // acc for q | 1
    const float s4e = __shfl_xor(vE, 4, 64);
    const float s4o = __shfl_xor(vO, 4, 64);
    float aqv[4];
    aqv[0] = q2b ? s4e : vE;
    aqv[1] = q2b ? s4o : vO;
    aqv[2] = q2b ? vE : s4e;
    aqv[3] = q2b ? vO : s4o;

    // ---- B: per-thread middle (redundant across the row's 8 threads) ----
    float xp[4];
    #pragma unroll
    for (int q = 0; q < 4; ++q) {
      const float e = __expf(2.0f * (aqv[q] + bi[q]));
      xp[q] = 1.0f - __fdividef(2.0f, e + 1.0f);   // tanh, inf-safe
    }
    const float mu = 0.25f * (xp[0] + xp[1] + xp[2] + xp[3]);
    const float d0 = xp[0] - mu, d1 = xp[1] - mu, d2 = xp[2] - mu, d3 = xp[3] - mu;
    const float var = 0.25f * (d0 * d0 + d1 * d1 + d2 * d2 + d3 * d3);
    const float inv = rsqrtf(var + 1e-5f);

    float Ax[4], Ay[4], Az[4];
    #pragma unroll
    for (int i = 0; i < 4; ++i) {
      const float ang = ((i == 0 ? d0 : i == 1 ? d1 : i == 2 ? d2 : d3) * inv) * ga[i] + be[i];
      float sn, cs;
      __sincosf(ang, &sn, &cs);
      const float ax = sn * sn;                     // RX(t) then RZ(t)
      const float ay = -sn * cs;
      const float az = cs;
      const float ay2 = ay * cw0[i] - az * sw0[i];  // RX(w0)
      const float az2 = ay * sw0[i] + az * cw0[i];
      const float ax3 = ax * cw1[i] - ay2 * sw1[i]; // RZ(w1)
      const float ay3 = ax * sw1[i] + ay2 * cw1[i];
      Ax[i] = ax3; Ay[i] = ay3; Az[i] = az2;
    }

    if ((tid & 7) == 0) {   // one writer per row
      float4 w0v = make_float4(Ax[0], Ay[0], Az[0], Ax[1]);
      float4 w1v = make_float4(Ay[1], Az[1], Ax[2], Ay[2]);
      float4 w2v = make_float4(Az[2], Ax[3], Ay[3], Az[3]);
      *reinterpret_cast<float4*>(&bs[ar][0]) = w0v;
      *reinterpret_cast<float4*>(&bs[ar][4]) = w1v;
      *reinterpret_cast<float4*>(&bs[ar][8]) = w2v;
    }
    __syncthreads();

    // ---- C: pairwise Pauli-z + epilogue; 4 pairs per wave ----
    #pragma unroll 1
    for (int pp = 0; pp < 4; ++pp) {
      const int pair = (wav << 2) | pp;
      const int row  = pair * 2 + grp;

      const float4 bA = *reinterpret_cast<const float4*>(&bs[row][0]);
      const float4 bB = *reinterpret_cast<const float4*>(&bs[row][4]);
      const float4 bC = *reinterpret_cast<const float4*>(&bs[row][8]);
      // bA={Ax0,Ay0,Az0,Ax1}, bB={Ay1,Az1,Ax2,Ay2}, bC={Az2,Ax3,Ay3,Az3}

      const float b2 = sel3(p0s, bA.x, bA.y, bA.z) *
                       sel3(p1s, bA.w, bB.x, bB.y);
      const float bv0 = b2 * sel3(p2b,     bB.z, bB.w, bC.x);
      const float bv1 = b2 * sel3(p2b + 1, bB.z, bB.w, bC.x);

      float z[4];
      #pragma unroll
      for (int q = 0; q < 4; ++q) {
        const float s0 = tf[q][0].x + tf[q][0].y * bC.y + tf[q][0].z * bC.z + tf[q][0].w * bC.w;
        const float s1 = tf[q][1].x + tf[q][1].y * bC.y + tf[q][1].z * bC.z + tf[q][1].w * bC.w;
        z[q] = bv0 * s0 + bv1 * s1;
      }
      #pragma unroll
      for (int off = 1; off < 32; off <<= 1) {
        #pragma unroll
        for (int q = 0; q < 4; ++q) z[q] += __shfl_xor(z[q], off, 64);
      }

      const float4 xv0 = *reinterpret_cast<const float4*>(&xs[row][l * 4]);
      const float4 xv1 = *reinterpret_cast<const float4*>(&xs[row][128 + l * 4]);

      float4 o0, o1;
      o0.x = xv0.x + boutf[0].x + z[0] * woutf[0][0].x + z[1] * woutf[0][0].y + z[2] * woutf[0][0].z + z[3] * woutf[0][0].w;
      o0.y = xv0.y + boutf[0].y + z[0] * woutf[0][1].x + z[1] * woutf[0][1].y + z[2] * woutf[0][1].z + z[3] * woutf[0][1].w;
      o0.z = xv0.z + boutf[0].z + z[0] * woutf[0][2].x + z[1] * woutf[0][2].y + z[2] * woutf[0][2].z + z[3] * woutf[0][2].w;
      o0.w = xv0.w + boutf[0].w + z[0] * woutf[0][3].x + z[1] * woutf[0][3].y + z[2] * woutf[0][3].z + z[3] * woutf[0][3].w;
      o1.x = xv1.x + boutf[1].x + z[0] * woutf[1][0].x + z[1] * woutf[1][0].y + z[2] * woutf[1][0].z + z[3] * woutf[1][0].w;
      o1.y = xv1.y + boutf[1].y + z[0] * woutf[1][1].x + z[1] * woutf[1][1].y + z[2] * woutf[1][1].z + z[3] * woutf[1][1].w;
      o1.z = xv1.z + boutf[1].z + z[0] * woutf[1][2].x + z[1] * woutf[1][2].y + z[2] * woutf[1][2].z + z[3] * woutf[1][2].w;
      o1.w = xv1.w + boutf[1].w + z[0] * woutf[1][3].x + z[1] * woutf[1][3].y + z[2] * woutf[1][3].z + z[3] * woutf[1][3].w;

      const size_t gbase = (size_t)(r0 + row) * DIM + l * 4;
      *reinterpret_cast<float4*>(&out[gbase])       = o0;
      *reinterpret_cast<float4*>(&out[gbase + 128]) = o1;
    }
  }
}

extern "C" void kernel_launch(void* const* d_in, const int* in_sizes, int n_in,
                              void* d_out, int out_size, void* d_ws, size_t ws_size,
                              hipStream_t stream)
{
  const float* x     = (const float*)d_in[0];
  const float* Win   = (const float*)d_in[1];
  const float* b_in  = (const float*)d_in[2];
  const float* gamma = (const float*)d_in[3];
  const float* beta  = (const float*)d_in[4];
  const float* qw    = (const float*)d_in[5];
  const float* Wout  = (const float*)d_in[6];
  const float* b_out = (const float*)d_in[7];
  float* out = (float*)d_out;
  const int B = in_sizes[0] / DIM;

  // 768 blocks = 3 blocks/CU (LDS-limited; matches waves_per_eu(3,3)).
  hipLaunchKernelGGL(qlayer_fused_kernel, dim3(768), dim3(256), 0, stream,
                     x, Win, b_in, gamma, beta, qw, Wout, b_out, out, B);
}